// Round 6
// baseline (223.577 us; speedup 1.0000x reference)
//
#include <hip/hip_runtime.h>
#include <math.h>

// VectorQuantizer, MFMA filter + exact-fp32 rescore.  N=32768 rows x K=8192
// codes, dim 64.
//   R4: 301us (1 block/CU, latency-bound).  R5: 167us (4 blocks/CU; vq_main
//   116us, LDS-read-bound: 512 ds_read_b128/thread = ~51us/CU of LDS traffic).
// R6 change: 64 rows/wave (4 row-tiles of 16) instead of 32 — each B-fragment
// ds_read feeds 4 MFMAs instead of 2, halving LDS read traffic per MAC.
// RPB 128->256 (4 waves x 64 rows), KQ 2048->1024, grid (128,8)=1024 blocks
// -> still 4 blocks/CU.  LDS ~29KB, VGPR ~+16.
//
// Exact numpy-fp32 semantics preserved (absmax 0 since R2 — DO NOT TOUCH):
//   S = sequential __fmaf_rn chain c=0..63; normx = numpy pairwise(n=64);
//   d = fl(normx - 2S) (2S exact); argmin = lowest index on ties.
// bf16 MFMA S~ error <= ~2e-5; exact-d quantization ~3.8e-6: codes within
// HALF_DELTA=4e-5 of per-row S~max (per k-slice) are a guaranteed superset of
// the exact argmin.  They are rescored bit-exactly; (d_bits<<13|k) u64
// atomicMin = value-then-lowest-index.  8 k-slices merge in vq_out.

#define DIM      64
#define NCODE    8192
#define NROWS    32768
#define RPB      256               // rows per block: 4 waves x 4 row-tiles x 16
#define KQ       1024              // codes per block (gridDim.y = 8)
#define CHUNK    128               // codes staged in LDS at a time (16 KB)
#define NCHUNK   (KQ / CHUNK)      // 8
#define HALF_DELTA 4.0e-5f
#define CAND_CAP 2048

typedef __attribute__((ext_vector_type(8))) short frag8;   // 8 bf16
typedef __attribute__((ext_vector_type(4))) float f32x4;

__device__ __forceinline__ unsigned short f2bf_rne(float f) {
  unsigned u = __float_as_uint(f);
  return (unsigned short)((u + 0x7FFFu + ((u >> 16) & 1u)) >> 16);
}

// ---- kernel 0: codebook fp32 -> bf16 (RNE), 8192x64 = 1 MB in ws ----
__global__ __launch_bounds__(256) void cvt_emb(const float* __restrict__ emb,
                                               unsigned short* __restrict__ ebf) {
  const int i = (blockIdx.x * 256 + threadIdx.x) * 8;
  const float4 a = *(const float4*)(emb + i);
  const float4 c = *(const float4*)(emb + i + 4);
  union { unsigned short u[8]; uint4 v; } o;
  o.u[0] = f2bf_rne(a.x); o.u[1] = f2bf_rne(a.y);
  o.u[2] = f2bf_rne(a.z); o.u[3] = f2bf_rne(a.w);
  o.u[4] = f2bf_rne(c.x); o.u[5] = f2bf_rne(c.y);
  o.u[6] = f2bf_rne(c.z); o.u[7] = f2bf_rne(c.w);
  *(uint4*)(ebf + i) = o.v;
}

// ---- kernel 1: per (256-row group, 1024-code slice) ----
__global__ __launch_bounds__(256) void vq_main(
    const float* __restrict__ x, const float* __restrict__ emb,
    const unsigned short* __restrict__ ebf,
    unsigned long long* __restrict__ wsbest)
{
  __shared__ uint4 ldsB[CHUNK * 8];            // 16 KB bf16 codes (16B units)
  __shared__ float s_normx[RPB];
  __shared__ float s_mrow[RPB];
  __shared__ unsigned long long s_best[RPB];
  __shared__ unsigned s_cand[CAND_CAP];        // (row_l<<10 | k_local)
  __shared__ int s_cnt;

  const int tid  = threadIdx.x;
  const int lane = tid & 63;
  const int wave = tid >> 6;
  const int s    = lane & 15;                  // MFMA m / n index
  const int q    = lane >> 4;                  // MFMA quad
  const int rowbase = blockIdx.x * RPB;
  const int kbase   = blockIdx.y * KQ;
  const int b    = rowbase >> 10;
  const int hw0  = rowbase & 1023;             // multiple of 256; one image b
  const float* xb = x + (size_t)b * (DIM * 1024);

  if (tid == 0) s_cnt = 0;
  s_best[tid] = ~0ull;

  // normx for row rowbase+tid — numpy pairwise_sum(n=64), bit-exact, coalesced
  {
    float p[DIM];
#pragma unroll
    for (int c = 0; c < DIM; ++c) {
      const float v = xb[(size_t)c * 1024 + hw0 + tid];
      p[c] = __fmul_rn(v, v);
    }
    float r8[8];
#pragma unroll
    for (int j = 0; j < 8; ++j) {
      float ss = p[j];
#pragma unroll
      for (int m = 1; m < 8; ++m) ss = __fadd_rn(ss, p[m * 8 + j]);
      r8[j] = ss;
    }
    const float t0 = __fadd_rn(r8[0], r8[1]), t1 = __fadd_rn(r8[2], r8[3]);
    const float t2 = __fadd_rn(r8[4], r8[5]), t3 = __fadd_rn(r8[6], r8[7]);
    s_normx[tid] = __fadd_rn(__fadd_rn(t0, t1), __fadd_rn(t2, t3));
  }

  // A-frags: wave owns 64 rows = 4 row-tiles of 16.  A[m=s][k=q*8+j].
  frag8 afr[4][2];
#pragma unroll
  for (int rt = 0; rt < 4; ++rt) {
    const float* xp = xb + hw0 + wave * 64 + rt * 16 + s;
#pragma unroll
    for (int h = 0; h < 2; ++h) {
      frag8 f;
#pragma unroll
      for (int j = 0; j < 8; ++j)
        f[j] = (short)f2bf_rne(xp[(size_t)(h * 32 + q * 8 + j) * 1024]);
      afr[rt][h] = f;
    }
  }

  // LDS B layout: slot code*8 + (j ^ (code&7)) holds 16B chunk j of code.
  // Frag read (code = t*16+s): lbA -> chunk q (c 0..31), lbB -> chunk 4+q.
  const int lbA = s * 8 + ((q)     ^ (s & 7));
  const int lbB = s * 8 + ((4 + q) ^ (s & 7));
  const frag8* ldsF = (const frag8*)ldsB;

  // ---- sweep A: per-row max of S~ ----
  f32x4 smax[4];
#pragma unroll
  for (int rt = 0; rt < 4; ++rt) smax[rt] = (f32x4){-1e30f, -1e30f, -1e30f, -1e30f};

  for (int ch = 0; ch < NCHUNK; ++ch) {
    __syncthreads();
    {
      const int code = tid >> 1, half = tid & 1;   // 2 threads per code, 64B each
      const uint4* src = (const uint4*)(ebf + (size_t)(kbase + ch * CHUNK + code) * DIM) + half * 4;
      const int sw = code & 7;
#pragma unroll
      for (int j = 0; j < 4; ++j) ldsB[code * 8 + ((half * 4 + j) ^ sw)] = src[j];
    }
    __syncthreads();
#pragma unroll
    for (int t = 0; t < 8; ++t) {
      const frag8 b0 = ldsF[lbA + t * 128];
      const frag8 b1 = ldsF[lbB + t * 128];
#pragma unroll
      for (int rt = 0; rt < 4; ++rt) {
        f32x4 d = {0.f, 0.f, 0.f, 0.f};
        d = __builtin_amdgcn_mfma_f32_16x16x32_bf16(afr[rt][0], b0, d, 0, 0, 0);
        d = __builtin_amdgcn_mfma_f32_16x16x32_bf16(afr[rt][1], b1, d, 0, 0, 0);
        smax[rt][0] = fmaxf(smax[rt][0], d[0]);
        smax[rt][1] = fmaxf(smax[rt][1], d[1]);
        smax[rt][2] = fmaxf(smax[rt][2], d[2]);
        smax[rt][3] = fmaxf(smax[rt][3], d[3]);
      }
    }
  }

  // reduce over the 16 code-columns (lane&15); D row = q*4+r
#pragma unroll
  for (int rt = 0; rt < 4; ++rt)
#pragma unroll
    for (int r = 0; r < 4; ++r) {
      float v = smax[rt][r];
      v = fmaxf(v, __shfl_xor(v, 1, 64));
      v = fmaxf(v, __shfl_xor(v, 2, 64));
      v = fmaxf(v, __shfl_xor(v, 4, 64));
      v = fmaxf(v, __shfl_xor(v, 8, 64));
      if (s == 0) s_mrow[wave * 64 + rt * 16 + q * 4 + r] = v;
    }
  __syncthreads();

  float thr[4][4];
#pragma unroll
  for (int rt = 0; rt < 4; ++rt)
#pragma unroll
    for (int r = 0; r < 4; ++r)
      thr[rt][r] = s_mrow[wave * 64 + rt * 16 + q * 4 + r] - HALF_DELTA;

  // ---- sweep B: recompute S~ (bit-identical), emit candidates ----
  for (int ch = 0; ch < NCHUNK; ++ch) {
    __syncthreads();
    {
      const int code = tid >> 1, half = tid & 1;
      const uint4* src = (const uint4*)(ebf + (size_t)(kbase + ch * CHUNK + code) * DIM) + half * 4;
      const int sw = code & 7;
#pragma unroll
      for (int j = 0; j < 4; ++j) ldsB[code * 8 + ((half * 4 + j) ^ sw)] = src[j];
    }
    __syncthreads();
#pragma unroll
    for (int t = 0; t < 8; ++t) {
      const frag8 b0 = ldsF[lbA + t * 128];
      const frag8 b1 = ldsF[lbB + t * 128];
      const int kl = ch * CHUNK + t * 16 + s;
#pragma unroll
      for (int rt = 0; rt < 4; ++rt) {
        f32x4 d = {0.f, 0.f, 0.f, 0.f};
        d = __builtin_amdgcn_mfma_f32_16x16x32_bf16(afr[rt][0], b0, d, 0, 0, 0);
        d = __builtin_amdgcn_mfma_f32_16x16x32_bf16(afr[rt][1], b1, d, 0, 0, 0);
#pragma unroll
        for (int r = 0; r < 4; ++r) {
          if (d[r] >= thr[rt][r]) {
            const int pos = atomicAdd(&s_cnt, 1);
            if (pos < CAND_CAP)
              s_cand[pos] = ((unsigned)(wave * 64 + rt * 16 + q * 4 + r) << 10) | (unsigned)kl;
          }
        }
      }
    }
  }
  __syncthreads();

  // ---- exact rescore of candidates (bit-exact numpy fp32 pipeline) ----
  const int cnt = min(s_cnt, CAND_CAP);
  for (int i = tid; i < cnt; i += 256) {
    const unsigned e = s_cand[i];
    const int row_l = (int)(e >> 10);
    const int kg = kbase + (int)(e & 0x3FFu);
    const float* ep = emb + (size_t)kg * DIM;
    const float* xp = xb + hw0 + row_l;
    float S = 0.f;
#pragma unroll
    for (int c = 0; c < DIM; ++c) S = __fmaf_rn(xp[(size_t)c * 1024], ep[c], S);
    const float dd = __fsub_rn(s_normx[row_l], __fadd_rn(S, S));
    const unsigned long long pack =
        ((unsigned long long)__float_as_uint(dd) << 13) | (unsigned long long)kg;
    atomicMin(&s_best[row_l], pack);
  }
  __syncthreads();

  wsbest[(size_t)(rowbase + tid) * 8 + blockIdx.y] = s_best[tid];
}

// ---- kernel 2: merge slices, write indices + gather z_q ----
__global__ __launch_bounds__(256) void vq_out(
    const float* __restrict__ emb, const unsigned long long* __restrict__ wsbest,
    float* __restrict__ zq, float* __restrict__ idx_out)
{
  const int row = blockIdx.x * 256 + threadIdx.x;
  unsigned long long p = wsbest[(size_t)row * 8];
#pragma unroll
  for (int j = 1; j < 8; ++j) {
    const unsigned long long pj = wsbest[(size_t)row * 8 + j];
    if (pj < p) p = pj;                        // d-major, then lowest k
  }
  const int k = (int)(p & 0x1FFFull);
  idx_out[row] = (float)k;
  const int b = row >> 10, hw = row & 1023;
  const float* ep = emb + (size_t)k * DIM;
  float* zp = zq + (size_t)b * (DIM * 1024) + hw;
#pragma unroll
  for (int c = 0; c < DIM; ++c) zp[(size_t)c * 1024] = ep[c];
}

extern "C" void kernel_launch(void* const* d_in, const int* in_sizes, int n_in,
                              void* d_out, int out_size, void* d_ws, size_t ws_size,
                              hipStream_t stream) {
  const float* x   = (const float*)d_in[0];   // [32, 64, 32, 32] fp32
  const float* emb = (const float*)d_in[1];   // [8192, 64] fp32

  float* zq      = (float*)d_out;
  float* idx_out = zq + (size_t)NROWS * DIM;

  unsigned short*     ebf    = (unsigned short*)d_ws;                          // 1 MB
  unsigned long long* wsbest = (unsigned long long*)((char*)d_ws + (1 << 20)); // 2 MB

  cvt_emb<<<dim3(256), 256, 0, stream>>>(emb, ebf);
  vq_main<<<dim3(NROWS / RPB, NCODE / KQ), 256, 0, stream>>>(x, emb, ebf, wsbest);
  vq_out<<<dim3(NROWS / 256), 256, 0, stream>>>(emb, wsbest, zq, idx_out);
}

// Round 7
// 170.139 us; speedup vs baseline: 1.3141x; 1.3141x over previous
//
#include <hip/hip_runtime.h>
#include <math.h>

// VectorQuantizer, MFMA filter + exact-fp32 rescore.  N=32768 rows x K=8192
// codes, dim 64.
//   R4: 301us (1 blk/CU latency-bound).  R5: 167us (4 blk/CU, LDS-read-bound).
//   R6: 223us REGRESSION — 4 row-tiles halved LDS traffic but +48 live regs
//       pushed unified VGPR+AGPR past a residency step: occupancy 40->25%
//       (2 blk/CU), same MFMA/VALU busy-time stretched over fewer waves.
// R7 change: __launch_bounds__(256, 4) = cap 128 unified regs/wave -> 4
// waves/SIMD -> 4 blk/CU, keeping R6's 64-rows/wave tiling (LDS reads per MAC
// stay halved).  normx restructured to stream 8 loads at a time (bit-identical
// numpy pairwise order) to kill the p[64] entry-pressure spike.
//
// Exact numpy-fp32 semantics preserved (absmax 0 since R2 — DO NOT TOUCH):
//   S = sequential __fmaf_rn chain c=0..63; normx = numpy pairwise(n=64);
//   d = fl(normx - 2S) (2S exact); argmin = lowest index on ties.
// bf16 MFMA S~ error <= ~2e-5; exact-d quantization ~3.8e-6: codes within
// HALF_DELTA=4e-5 of per-row S~max (per k-slice) are a guaranteed superset of
// the exact argmin.  They are rescored bit-exactly; (d_bits<<13|k) u64
// atomicMin = value-then-lowest-index.  8 k-slices merge in vq_out.

#define DIM      64
#define NCODE    8192
#define NROWS    32768
#define RPB      256               // rows per block: 4 waves x 4 row-tiles x 16
#define KQ       1024              // codes per block (gridDim.y = 8)
#define CHUNK    128               // codes staged in LDS at a time (16 KB)
#define NCHUNK   (KQ / CHUNK)      // 8
#define HALF_DELTA 4.0e-5f
#define CAND_CAP 2048

typedef __attribute__((ext_vector_type(8))) short frag8;   // 8 bf16
typedef __attribute__((ext_vector_type(4))) float f32x4;

__device__ __forceinline__ unsigned short f2bf_rne(float f) {
  unsigned u = __float_as_uint(f);
  return (unsigned short)((u + 0x7FFFu + ((u >> 16) & 1u)) >> 16);
}

// ---- kernel 0: codebook fp32 -> bf16 (RNE), 8192x64 = 1 MB in ws ----
__global__ __launch_bounds__(256) void cvt_emb(const float* __restrict__ emb,
                                               unsigned short* __restrict__ ebf) {
  const int i = (blockIdx.x * 256 + threadIdx.x) * 8;
  const float4 a = *(const float4*)(emb + i);
  const float4 c = *(const float4*)(emb + i + 4);
  union { unsigned short u[8]; uint4 v; } o;
  o.u[0] = f2bf_rne(a.x); o.u[1] = f2bf_rne(a.y);
  o.u[2] = f2bf_rne(a.z); o.u[3] = f2bf_rne(a.w);
  o.u[4] = f2bf_rne(c.x); o.u[5] = f2bf_rne(c.y);
  o.u[6] = f2bf_rne(c.z); o.u[7] = f2bf_rne(c.w);
  *(uint4*)(ebf + i) = o.v;
}

// ---- kernel 1: per (256-row group, 1024-code slice) ----
__global__ __launch_bounds__(256, 4) void vq_main(
    const float* __restrict__ x, const float* __restrict__ emb,
    const unsigned short* __restrict__ ebf,
    unsigned long long* __restrict__ wsbest)
{
  __shared__ uint4 ldsB[CHUNK * 8];            // 16 KB bf16 codes (16B units)
  __shared__ float s_normx[RPB];
  __shared__ float s_mrow[RPB];
  __shared__ unsigned long long s_best[RPB];
  __shared__ unsigned s_cand[CAND_CAP];        // (row_l<<10 | k_local)
  __shared__ int s_cnt;

  const int tid  = threadIdx.x;
  const int lane = tid & 63;
  const int wave = tid >> 6;
  const int s    = lane & 15;                  // MFMA m / n index
  const int q    = lane >> 4;                  // MFMA quad
  const int rowbase = blockIdx.x * RPB;
  const int kbase   = blockIdx.y * KQ;
  const int b    = rowbase >> 10;
  const int hw0  = rowbase & 1023;             // multiple of 256; one image b
  const float* xb = x + (size_t)b * (DIM * 1024);

  if (tid == 0) s_cnt = 0;
  s_best[tid] = ~0ull;

  // normx — numpy pairwise_sum(n=64) bit-exact, streamed 8 loads at a time:
  // r8[j] = p[j] + p[8+j] + ... + p[56+j] (ascending m), then the fixed tree.
  {
    float r8[8];
#pragma unroll
    for (int m = 0; m < 8; ++m) {
#pragma unroll
      for (int j = 0; j < 8; ++j) {
        const float v = xb[(size_t)(m * 8 + j) * 1024 + hw0 + tid];
        const float pv = __fmul_rn(v, v);
        r8[j] = (m == 0) ? pv : __fadd_rn(r8[j], pv);
      }
    }
    const float t0 = __fadd_rn(r8[0], r8[1]), t1 = __fadd_rn(r8[2], r8[3]);
    const float t2 = __fadd_rn(r8[4], r8[5]), t3 = __fadd_rn(r8[6], r8[7]);
    s_normx[tid] = __fadd_rn(__fadd_rn(t0, t1), __fadd_rn(t2, t3));
  }

  // A-frags: wave owns 64 rows = 4 row-tiles of 16.  A[m=s][k=q*8+j].
  frag8 afr[4][2];
#pragma unroll
  for (int rt = 0; rt < 4; ++rt) {
    const float* xp = xb + hw0 + wave * 64 + rt * 16 + s;
#pragma unroll
    for (int h = 0; h < 2; ++h) {
      frag8 f;
#pragma unroll
      for (int j = 0; j < 8; ++j)
        f[j] = (short)f2bf_rne(xp[(size_t)(h * 32 + q * 8 + j) * 1024]);
      afr[rt][h] = f;
    }
  }

  // LDS B layout: slot code*8 + (j ^ (code&7)) holds 16B chunk j of code.
  // Frag read (code = t*16+s): lbA -> chunk q (c 0..31), lbB -> chunk 4+q.
  const int lbA = s * 8 + ((q)     ^ (s & 7));
  const int lbB = s * 8 + ((4 + q) ^ (s & 7));
  const frag8* ldsF = (const frag8*)ldsB;

  // ---- sweep A: per-row max of S~ ----
  f32x4 smax[4];
#pragma unroll
  for (int rt = 0; rt < 4; ++rt) smax[rt] = (f32x4){-1e30f, -1e30f, -1e30f, -1e30f};

  for (int ch = 0; ch < NCHUNK; ++ch) {
    __syncthreads();
    {
      const int code = tid >> 1, half = tid & 1;   // 2 threads per code, 64B each
      const uint4* src = (const uint4*)(ebf + (size_t)(kbase + ch * CHUNK + code) * DIM) + half * 4;
      const int sw = code & 7;
#pragma unroll
      for (int j = 0; j < 4; ++j) ldsB[code * 8 + ((half * 4 + j) ^ sw)] = src[j];
    }
    __syncthreads();
#pragma unroll
    for (int t = 0; t < 8; ++t) {
      const frag8 b0 = ldsF[lbA + t * 128];
      const frag8 b1 = ldsF[lbB + t * 128];
#pragma unroll
      for (int rt = 0; rt < 4; ++rt) {
        f32x4 d = {0.f, 0.f, 0.f, 0.f};
        d = __builtin_amdgcn_mfma_f32_16x16x32_bf16(afr[rt][0], b0, d, 0, 0, 0);
        d = __builtin_amdgcn_mfma_f32_16x16x32_bf16(afr[rt][1], b1, d, 0, 0, 0);
        smax[rt][0] = fmaxf(smax[rt][0], d[0]);
        smax[rt][1] = fmaxf(smax[rt][1], d[1]);
        smax[rt][2] = fmaxf(smax[rt][2], d[2]);
        smax[rt][3] = fmaxf(smax[rt][3], d[3]);
      }
    }
  }

  // reduce over the 16 code-columns (lane&15); D row = q*4+r
#pragma unroll
  for (int rt = 0; rt < 4; ++rt)
#pragma unroll
    for (int r = 0; r < 4; ++r) {
      float v = smax[rt][r];
      v = fmaxf(v, __shfl_xor(v, 1, 64));
      v = fmaxf(v, __shfl_xor(v, 2, 64));
      v = fmaxf(v, __shfl_xor(v, 4, 64));
      v = fmaxf(v, __shfl_xor(v, 8, 64));
      if (s == 0) s_mrow[wave * 64 + rt * 16 + q * 4 + r] = v;
    }
  __syncthreads();

  float thr[4][4];
#pragma unroll
  for (int rt = 0; rt < 4; ++rt)
#pragma unroll
    for (int r = 0; r < 4; ++r)
      thr[rt][r] = s_mrow[wave * 64 + rt * 16 + q * 4 + r] - HALF_DELTA;

  // ---- sweep B: recompute S~ (bit-identical), emit candidates ----
  for (int ch = 0; ch < NCHUNK; ++ch) {
    __syncthreads();
    {
      const int code = tid >> 1, half = tid & 1;
      const uint4* src = (const uint4*)(ebf + (size_t)(kbase + ch * CHUNK + code) * DIM) + half * 4;
      const int sw = code & 7;
#pragma unroll
      for (int j = 0; j < 4; ++j) ldsB[code * 8 + ((half * 4 + j) ^ sw)] = src[j];
    }
    __syncthreads();
#pragma unroll
    for (int t = 0; t < 8; ++t) {
      const frag8 b0 = ldsF[lbA + t * 128];
      const frag8 b1 = ldsF[lbB + t * 128];
      const int kl = ch * CHUNK + t * 16 + s;
#pragma unroll
      for (int rt = 0; rt < 4; ++rt) {
        f32x4 d = {0.f, 0.f, 0.f, 0.f};
        d = __builtin_amdgcn_mfma_f32_16x16x32_bf16(afr[rt][0], b0, d, 0, 0, 0);
        d = __builtin_amdgcn_mfma_f32_16x16x32_bf16(afr[rt][1], b1, d, 0, 0, 0);
#pragma unroll
        for (int r = 0; r < 4; ++r) {
          if (d[r] >= thr[rt][r]) {
            const int pos = atomicAdd(&s_cnt, 1);
            if (pos < CAND_CAP)
              s_cand[pos] = ((unsigned)(wave * 64 + rt * 16 + q * 4 + r) << 10) | (unsigned)kl;
          }
        }
      }
    }
  }
  __syncthreads();

  // ---- exact rescore of candidates (bit-exact numpy fp32 pipeline) ----
  const int cnt = min(s_cnt, CAND_CAP);
  for (int i = tid; i < cnt; i += 256) {
    const unsigned e = s_cand[i];
    const int row_l = (int)(e >> 10);
    const int kg = kbase + (int)(e & 0x3FFu);
    const float* ep = emb + (size_t)kg * DIM;
    const float* xp = xb + hw0 + row_l;
    float S = 0.f;
#pragma unroll
    for (int c = 0; c < DIM; ++c) S = __fmaf_rn(xp[(size_t)c * 1024], ep[c], S);
    const float dd = __fsub_rn(s_normx[row_l], __fadd_rn(S, S));
    const unsigned long long pack =
        ((unsigned long long)__float_as_uint(dd) << 13) | (unsigned long long)kg;
    atomicMin(&s_best[row_l], pack);
  }
  __syncthreads();

  wsbest[(size_t)(rowbase + tid) * 8 + blockIdx.y] = s_best[tid];
}

// ---- kernel 2: merge slices, write indices + gather z_q ----
__global__ __launch_bounds__(256) void vq_out(
    const float* __restrict__ emb, const unsigned long long* __restrict__ wsbest,
    float* __restrict__ zq, float* __restrict__ idx_out)
{
  const int row = blockIdx.x * 256 + threadIdx.x;
  unsigned long long p = wsbest[(size_t)row * 8];
#pragma unroll
  for (int j = 1; j < 8; ++j) {
    const unsigned long long pj = wsbest[(size_t)row * 8 + j];
    if (pj < p) p = pj;                        // d-major, then lowest k
  }
  const int k = (int)(p & 0x1FFFull);
  idx_out[row] = (float)k;
  const int b = row >> 10, hw = row & 1023;
  const float* ep = emb + (size_t)k * DIM;
  float* zp = zq + (size_t)b * (DIM * 1024) + hw;
#pragma unroll
  for (int c = 0; c < DIM; ++c) zp[(size_t)c * 1024] = ep[c];
}

extern "C" void kernel_launch(void* const* d_in, const int* in_sizes, int n_in,
                              void* d_out, int out_size, void* d_ws, size_t ws_size,
                              hipStream_t stream) {
  const float* x   = (const float*)d_in[0];   // [32, 64, 32, 32] fp32
  const float* emb = (const float*)d_in[1];   // [8192, 64] fp32

  float* zq      = (float*)d_out;
  float* idx_out = zq + (size_t)NROWS * DIM;

  unsigned short*     ebf    = (unsigned short*)d_ws;                          // 1 MB
  unsigned long long* wsbest = (unsigned long long*)((char*)d_ws + (1 << 20)); // 2 MB

  cvt_emb<<<dim3(256), 256, 0, stream>>>(emb, ebf);
  vq_main<<<dim3(NROWS / RPB, NCODE / KQ), 256, 0, stream>>>(x, emb, ebf, wsbest);
  vq_out<<<dim3(NROWS / 256), 256, 0, stream>>>(emb, wsbest, zq, idx_out);
}